// Round 9
// baseline (291.110 us; speedup 1.0000x reference)
//
#include <hip/hip_runtime.h>
#include <math.h>

#define DIM   2048
#define NREF  30
#define KPAD  32
#define BATCH 16384

#define MSTRIDE   80          // bytes per m-row inside a kstep frag block (16B-aligned, bank-spread)
#define KSSTRIDE  1296        // 16*80 + 16 pad (16B-aligned)
#define WAVEREG   (4 * KSSTRIDE)   // 4 ksteps resident per wave = 5184 B

typedef __attribute__((ext_vector_type(8))) short short8;
typedef __attribute__((ext_vector_type(4))) float f32x4;
typedef __attribute__((ext_vector_type(2))) float f32x2;

// Workspace float offsets
#define WS_VN   0         // 30*2048 fp32
#define WS_G    61440     // 1024
#define WS_T    62464     // 1024
#define WS_FP1  63488     // bf16 B-frags of W2: [64 kstep][2 ntile][64 lane][8]  (128 KB)

__device__ __forceinline__ unsigned short f2bf(float f) {
    unsigned u = __float_as_uint(f);
    u += 0x7FFF + ((u >> 16) & 1);          // round-to-nearest-even
    return (unsigned short)(u >> 16);
}

// ---- prep: blocks 0..29 normalize rows; blocks 30..929 compute G from raw vec ----
__global__ void k_prep(const float* __restrict__ vec, float* __restrict__ vn,
                       float* __restrict__ G) {
    int b = blockIdx.x, t = threadIdx.x;
    __shared__ float wsum[3][4];
    if (b < NREF) {
        const float* v = vec + b * DIM;
        float s = 0.f;
        for (int d = t; d < DIM; d += 256) { float xv = v[d]; s += xv * xv; }
        #pragma unroll
        for (int off = 32; off > 0; off >>= 1) s += __shfl_down(s, off);
        if ((t & 63) == 0) wsum[0][t >> 6] = s;
        __syncthreads();
        float tot = wsum[0][0] + wsum[0][1] + wsum[0][2] + wsum[0][3];
        float scale = 1.f / (sqrtf(tot) + 1e-8f);
        float* o = vn + b * DIM;
        for (int d = t; d < DIM; d += 256) o[d] = v[d] * scale;
    } else {
        int idx = b - NREF;
        int i = idx / NREF, j = idx % NREF;
        const float* a = vec + i * DIM;
        const float* c = vec + j * DIM;
        float sab = 0.f, saa = 0.f, sbb = 0.f;
        for (int d = t; d < DIM; d += 256) {
            float av = a[d], cv = c[d];
            sab += av * cv; saa += av * av; sbb += cv * cv;
        }
        #pragma unroll
        for (int off = 32; off > 0; off >>= 1) {
            sab += __shfl_down(sab, off);
            saa += __shfl_down(saa, off);
            sbb += __shfl_down(sbb, off);
        }
        if ((t & 63) == 0) { wsum[0][t >> 6] = sab; wsum[1][t >> 6] = saa; wsum[2][t >> 6] = sbb; }
        __syncthreads();
        if (t == 0) {
            float tab = wsum[0][0] + wsum[0][1] + wsum[0][2] + wsum[0][3];
            float taa = wsum[1][0] + wsum[1][1] + wsum[1][2] + wsum[1][3];
            float tbb = wsum[2][0] + wsum[2][1] + wsum[2][2] + wsum[2][3];
            G[i * NREF + j] = tab / ((sqrtf(taa) + 1e-8f) * (sqrtf(tbb) + 1e-8f));
        }
    }
}

// ---- T: per-ROW recurrence, G cached in LDS, zero cross-thread deps ----
__global__ void k_T2(const float* __restrict__ G, float* __restrict__ T) {
    int t = threadIdx.x;  // 64 threads
    __shared__ float Gs[NREF * NREF];
    __shared__ float Ts[NREF][NREF];
    for (int idx = t; idx < NREF * NREF; idx += 64) {
        Gs[idx] = G[idx];
        Ts[idx / NREF][idx % NREF] = 0.f;
    }
    __syncthreads();
    if (t < NREF) {
        Ts[t][t] = 2.f;
        for (int j = t + 1; j < NREF; j++) {
            float val = 0.f;
            for (int mm = t; mm < j; mm++) val += Ts[t][mm] * Gs[mm * NREF + j];
            Ts[t][j] = -2.f * val;
        }
    }
    __syncthreads();
    for (int idx = t; idx < NREF * NREF; idx += 64) T[idx] = Ts[idx / NREF][idx % NREF];
}

// ---- mid: W2 (in LDS) + pack1 for the phase-A MFMA B operand ----
__global__ void k_mid(const float* __restrict__ vn, const float* __restrict__ T,
                      unsigned short* __restrict__ fp1) {
    int b = blockIdx.x, t = threadIdx.x;
    __shared__ float W2s[256][33];
    int d = b * 256 + t;
    float vr[NREF];
    #pragma unroll
    for (int j = 0; j < NREF; j++) vr[j] = vn[j * DIM + d];
    #pragma unroll
    for (int k = 0; k < KPAD; k++) {
        float acc = 0.f;
        if (k < NREF)
            for (int j = 0; j <= k; j++) acc += vr[j] * T[j * NREF + k];
        W2s[t][k] = acc;
    }
    __syncthreads();
    short8* out = (short8*)fp1;
    #pragma unroll
    for (int u = 0; u < 4; u++) {
        int lf = t * 4 + u;
        int ks_l = lf >> 7, nt = (lf >> 6) & 1, lane = lf & 63;
        int q = lane >> 4, n = lane & 15;
        short8 v;
        #pragma unroll
        for (int j = 0; j < 8; j++)
            v[j] = (short)f2bf(W2s[ks_l * 32 + q * 8 + j][nt * 16 + n]);
        out[((b * 8 + ks_l) * 2 + nt) * 64 + lane] = v;
    }
}

// ---- fused per-block: block owns 16 rows.
// Phase A (rebuilt): S = x*W2 via MFMA, but x is loaded LINE-DENSE (per instr:
// 2 rows x 512 contiguous bytes = 16 full cache lines) instead of the A-layout
// scatter (half-line density -> ~2.1 TB/s, the r1-r8 wall). Each wave owns its
// 512-col K-range; per 128-col quarter it loads 8 coalesced f32x4, converts to
// bf16, writes granules DIRECTLY at A-frag positions in wave-private LDS, reads
// back b128 frags, MFMAs. Wave-private -> NO barriers in the K loop (same-wave
// DS is in-order; lgkmcnt(0)+sched_barrier belt-and-suspenders per rule 18).
// LDS 31 KB -> 4 blocks/CU, grid 1024 = 4x256 exact (no tail round).
// Phase B: r8's passing VALU stream, verbatim.
__global__ __launch_bounds__(256, 4) void k_fused(const float* __restrict__ x,
                                                  const short8* __restrict__ fp1,
                                                  const float* __restrict__ vn,
                                                  const float* __restrict__ bias,
                                                  float* __restrict__ y) {
    __shared__ __align__(16) char xfrag[4 * WAVEREG];   // 20736 B
    __shared__ f32x4 red[4][64][2];                     // 8 KB
    __shared__ float Sf[16][KPAD];                      // 2 KB
    int tid = threadIdx.x;
    int wave = tid >> 6, lane = tid & 63;
    int m = lane & 15, q = lane >> 4;
    int r0 = blockIdx.x * 16;

    // ================= phase A: S = x * W2 =================
    {
        int kb = wave * 512;
        int lk = lane & 31;                 // position within a row-half
        int g  = lane >> 5;                 // which row of the pair
        // global load base: row pair p covers rows {2p+g}, cols kb+Q*128+lk*4
        const float* xq = x + (size_t)(r0 + g) * DIM + kb + lk * 4;
        // LDS write slot: frag[ks=lk>>3][row][q=(lk>>1)&3][j=(lane&1)*4]
        char* wptr = xfrag + wave * WAVEREG + (lk >> 3) * KSSTRIDE
                   + g * MSTRIDE + ((lk >> 1) & 3) * 16 + (lane & 1) * 8;
        // LDS read base for this lane's A-frag
        const char* rbase = xfrag + wave * WAVEREG + m * MSTRIDE + q * 16;

        f32x4 acc0 = {0.f, 0.f, 0.f, 0.f};
        f32x4 acc1 = {0.f, 0.f, 0.f, 0.f};

        #pragma unroll
        for (int Q = 0; Q < 4; Q++) {
            // 8 line-dense loads: instr p = rows {2p,2p+1} x 512 B contiguous each
            f32x4 ld[8];
            #pragma unroll
            for (int p = 0; p < 8; p++)
                ld[p] = *(const f32x4*)(xq + (size_t)(2 * p) * DIM + Q * 128);

            // prev quarter's frag reads complete before overwrite
            asm volatile("s_waitcnt lgkmcnt(0)" ::: "memory");
            __builtin_amdgcn_sched_barrier(0);

            #pragma unroll
            for (int p = 0; p < 8; p++) {
                unsigned d0 = (unsigned)f2bf(ld[p][0]) | ((unsigned)f2bf(ld[p][1]) << 16);
                unsigned d1 = (unsigned)f2bf(ld[p][2]) | ((unsigned)f2bf(ld[p][3]) << 16);
                *(uint2*)(wptr + p * (2 * MSTRIDE)) = make_uint2(d0, d1);
            }

            asm volatile("s_waitcnt lgkmcnt(0)" ::: "memory");  // writes visible to wave
            __builtin_amdgcn_sched_barrier(0);

            #pragma unroll
            for (int ks = 0; ks < 4; ks++) {
                short8 a = *(const short8*)(rbase + ks * KSSTRIDE);
                int ksg = wave * 16 + Q * 4 + ks;
                short8 b0 = fp1[(ksg * 2 + 0) * 64 + lane];
                short8 b1 = fp1[(ksg * 2 + 1) * 64 + lane];
                acc0 = __builtin_amdgcn_mfma_f32_16x16x32_bf16(a, b0, acc0, 0, 0, 0);
                acc1 = __builtin_amdgcn_mfma_f32_16x16x32_bf16(a, b1, acc1, 0, 0, 0);
            }
        }

        red[wave][lane][0] = acc0;
        red[wave][lane][1] = acc1;
        __syncthreads();
        if (tid < 64) {
            f32x4 s0 = red[0][tid][0], s1 = red[0][tid][1];
            #pragma unroll
            for (int w = 1; w < 4; w++) { s0 += red[w][tid][0]; s1 += red[w][tid][1]; }
            int mq = tid & 15, qq = tid >> 4;
            #pragma unroll
            for (int reg = 0; reg < 4; reg++) {
                Sf[qq * 4 + reg][mq]      = s0[reg];
                Sf[qq * 4 + reg][16 + mq] = s1[reg];
            }
        }
        __syncthreads();
    }

    // ================= phase B: y = x + bias - S * vn =================
    const float* xr = x + (size_t)r0 * DIM;
    float* yr = y + (size_t)r0 * DIM;

    #pragma unroll 1
    for (int pass = 0; pass < 4; pass++) {
        int cl = pass * 512 + tid * 2;       // lane-contiguous col pair
        f32x2 vt[32];
        #pragma unroll
        for (int n = 0; n < NREF; n++)
            vt[n] = *(const f32x2*)(vn + n * DIM + cl);
        vt[30] = (f32x2){0.f, 0.f};
        vt[31] = (f32x2){0.f, 0.f};
        f32x2 bi = *(const f32x2*)(bias + cl);

        #pragma unroll 4
        for (int r = 0; r < 16; r++) {
            f32x2 xv = *(const f32x2*)(xr + (size_t)r * DIM + cl);
            f32x2 acc = xv + bi;
            const float* Sr = &Sf[r][0];
            #pragma unroll
            for (int n4 = 0; n4 < 8; n4++) {          // b128 broadcast S reads
                f32x4 s4 = *(const f32x4*)&Sr[n4 * 4];
                acc -= s4[0] * vt[n4 * 4 + 0];
                acc -= s4[1] * vt[n4 * 4 + 1];
                acc -= s4[2] * vt[n4 * 4 + 2];
                acc -= s4[3] * vt[n4 * 4 + 3];        // S[:,30..31]==0 -> safe
            }
            __builtin_nontemporal_store(acc, (f32x2*)(yr + (size_t)r * DIM + cl));
        }
    }
}

extern "C" void kernel_launch(void* const* d_in, const int* in_sizes, int n_in,
                              void* d_out, int out_size, void* d_ws, size_t ws_size,
                              hipStream_t stream) {
    const float* x    = (const float*)d_in[0];
    const float* vec  = (const float*)d_in[1];
    const float* bias = (const float*)d_in[2];
    float* out = (float*)d_out;
    float* ws  = (float*)d_ws;

    float* vn = ws + WS_VN;
    float* G  = ws + WS_G;
    float* T  = ws + WS_T;
    unsigned short* fp1 = (unsigned short*)(ws + WS_FP1);

    k_prep<<<NREF + NREF * NREF, 256, 0, stream>>>(vec, vn, G);
    k_T2<<<1, 64, 0, stream>>>(G, T);
    k_mid<<<8, 256, 0, stream>>>(vn, T, fp1);
    k_fused<<<BATCH / 16, 256, 0, stream>>>(x, (const short8*)fp1, vn, bias, out);
}